// Round 1
// baseline (1878.147 us; speedup 1.0000x reference)
//
#include <hip/hip_runtime.h>
#include <math.h>

#define S 1024
#define DM 2048
#define NH 16
#define NKV 4
#define HD 128
#define NE 8
#define FF 2048
#define QKVN 3072

typedef float f32x4 __attribute__((ext_vector_type(4)));
typedef short bf16x8 __attribute__((ext_vector_type(8)));
typedef unsigned short u16;

__device__ __forceinline__ u16 f2bf(float x) {
    union { float f; unsigned u; } v; v.f = x;
    unsigned r = v.u + 0x7FFFu + ((v.u >> 16) & 1u);
    return (u16)(r >> 16);
}

enum { BL_KN_F32 = 0, BL_NK_F32 = 1, BL_KN_BF16 = 2, BL_NK_BF16 = 3 };
enum { EPI_CLIP = 0, EPI_RESID = 1, EPI_SCORES = 2, EPI_BF16 = 3, EPI_F32 = 4,
       EPI_SILUMUL = 5, EPI_SCATTER = 6 };

// ---------------------------------------------------------------------------
// Generic 128x128-tile MFMA bf16 GEMM.  4 waves in 2x2, each wave does a
// 64x64 region as 4x4 tiles of 16x16x32 MFMA.  BK=32 per K-step.
// A is always bf16 (raw u16), row-major MxK with optional row remap (a_idx).
// B layout/dtype per BL; staged into LDS as B^T [n][k] bf16.
// ---------------------------------------------------------------------------
template<int BL, int EPI, bool KLIM>
__global__ __launch_bounds__(256) void gemm_kernel(
    const u16* __restrict__ Abase, long lda, long strideAz,
    const void* __restrict__ Bbase, long ldb, long strideBz, int zdivB,
    void* __restrict__ Cbase, long ldc, long strideCz,
    int M, int K,
    const int* __restrict__ a_idx,     // per-z stride S (A row remap)
    const int* __restrict__ out_idx,   // per-z stride S (C row scatter)
    const float* __restrict__ gatesb,  // per-z stride S
    const int* __restrict__ cntp,      // per-z M override
    const float* __restrict__ aux0, long strideAux,
    float* __restrict__ aux1,
    const int* __restrict__ amask)
{
    const int z  = blockIdx.z;
    if (cntp) M = cntp[z];
    const int bm = blockIdx.y, bn = blockIdx.x;
    if (bm * 128 >= M) return;

    const int tid  = threadIdx.x;
    const int lane = tid & 63, wave = tid >> 6;
    const int ln = lane & 15, quad = lane >> 4;
    const int wm = wave >> 1, wn = wave & 1;

    // fast path: fully-masked causal score tiles
    if (EPI == EPI_SCORES && bn > bm) {
        float* C = (float*)Cbase + (size_t)z * strideCz;
        const float4 mv = make_float4(-3.0e38f, -3.0e38f, -3.0e38f, -3.0e38f);
        for (int t = tid; t < 128 * 32; t += 256) {
            int row = t >> 5, c4 = (t & 31) * 4;
            *(float4*)&C[(size_t)(bm * 128 + row) * ldc + bn * 128 + c4] = mv;
        }
        return;
    }

    const u16* A = Abase + (size_t)z * strideAz;
    constexpr int besz = (BL == BL_KN_F32 || BL == BL_NK_F32) ? 4 : 2;
    const char* B = (const char*)Bbase + (size_t)(z / zdivB) * strideBz * besz;

    __shared__ u16 lA[128 * 40];
    __shared__ u16 lB[128 * 40];

    f32x4 acc[4][4];
    for (int i = 0; i < 4; i++)
        for (int j = 0; j < 4; j++)
            acc[i][j] = (f32x4){0.f, 0.f, 0.f, 0.f};

    const int kmax = KLIM ? ((K < (bm + 1) * 128) ? K : (bm + 1) * 128) : K;

    for (int k0 = 0; k0 < kmax; k0 += 32) {
        __syncthreads();
        // ---- stage A: 128 rows x 32 k
        for (int rep = 0; rep < 2; rep++) {
            int m  = rep * 64 + (tid >> 2);
            int kk = (tid & 3) * 8;
            int gm = bm * 128 + m;
            uint4 val = {0u, 0u, 0u, 0u};
            if (gm < M) {
                long row = a_idx ? (long)a_idx[(size_t)z * S + gm] : (long)gm;
                val = *(const uint4*)(A + row * lda + k0 + kk);
            }
            *(uint4*)&lA[m * 40 + kk] = val;
        }
        // ---- stage B -> lB as B^T[n][k]
        if constexpr (BL == BL_NK_F32) {
            const float* Bf = (const float*)B;
            for (int rep = 0; rep < 2; rep++) {
                int n  = rep * 64 + (tid >> 2);
                int kk = (tid & 3) * 8;
                const float* src = Bf + (size_t)(bn * 128 + n) * ldb + k0 + kk;
                float4 f0 = *(const float4*)src;
                float4 f1 = *(const float4*)(src + 4);
                u16 t8[8] = { f2bf(f0.x), f2bf(f0.y), f2bf(f0.z), f2bf(f0.w),
                              f2bf(f1.x), f2bf(f1.y), f2bf(f1.z), f2bf(f1.w) };
                *(uint4*)&lB[n * 40 + kk] = *(uint4*)t8;
            }
        } else if constexpr (BL == BL_NK_BF16) {
            const u16* Bb = (const u16*)B;
            for (int rep = 0; rep < 2; rep++) {
                int n  = rep * 64 + (tid >> 2);
                int kk = (tid & 3) * 8;
                uint4 val = *(const uint4*)(Bb + (size_t)(bn * 128 + n) * ldb + k0 + kk);
                *(uint4*)&lB[n * 40 + kk] = val;
            }
        } else if constexpr (BL == BL_KN_F32) {
            const float* Bf = (const float*)B;
            for (int rep = 0; rep < 2; rep++) {
                int k  = rep * 16 + (tid >> 4);
                int n0 = (tid & 15) * 8;
                const float* src = Bf + (size_t)(k0 + k) * ldb + bn * 128 + n0;
                float4 f0 = *(const float4*)src;
                float4 f1 = *(const float4*)(src + 4);
                u16 t8[8] = { f2bf(f0.x), f2bf(f0.y), f2bf(f0.z), f2bf(f0.w),
                              f2bf(f1.x), f2bf(f1.y), f2bf(f1.z), f2bf(f1.w) };
                for (int i = 0; i < 8; i++) lB[(n0 + i) * 40 + k] = t8[i];
            }
        } else { // BL_KN_BF16
            const u16* Bb = (const u16*)B;
            for (int rep = 0; rep < 2; rep++) {
                int k  = rep * 16 + (tid >> 4);
                int n0 = (tid & 15) * 8;
                const u16* src = Bb + (size_t)(k0 + k) * ldb + bn * 128 + n0;
                u16 t8[8];
                *(uint4*)t8 = *(const uint4*)src;
                for (int i = 0; i < 8; i++) lB[(n0 + i) * 40 + k] = t8[i];
            }
        }
        __syncthreads();
        // ---- MFMA
        bf16x8 af[4], bfr[4];
        for (int i = 0; i < 4; i++)
            af[i] = *(const bf16x8*)&lA[(wm * 64 + i * 16 + ln) * 40 + quad * 8];
        for (int j = 0; j < 4; j++)
            bfr[j] = *(const bf16x8*)&lB[(wn * 64 + j * 16 + ln) * 40 + quad * 8];
        for (int i = 0; i < 4; i++)
            for (int j = 0; j < 4; j++)
                acc[i][j] = __builtin_amdgcn_mfma_f32_16x16x32_bf16(af[i], bfr[j], acc[i][j], 0, 0, 0);
    }

    // ---- epilogue
    const int baserow = bm * 128 + wm * 64;
    const int basecol = bn * 128 + wn * 64;
    for (int i = 0; i < 4; i++) {
        for (int j = 0; j < 4; j++) {
#pragma unroll
            for (int r = 0; r < 4; r++) {
                int gm = baserow + i * 16 + quad * 4 + r;
                int gn = basecol + j * 16 + ln;
                if (gm >= M) continue;
                float v = acc[i][j][r];
                if constexpr (EPI == EPI_CLIP) {
                    float* C = (float*)Cbase + (size_t)z * strideCz;
                    C[(size_t)gm * ldc + gn] = fminf(fmaxf(v, -8.f), 8.f);
                } else if constexpr (EPI == EPI_SCORES) {
                    float* C = (float*)Cbase + (size_t)z * strideCz;
                    float sv = v * 0.08838834764831845f;
                    if (gn > gm || amask[gn] == 0) sv = -3.0e38f;
                    C[(size_t)gm * ldc + gn] = sv;
                } else if constexpr (EPI == EPI_RESID) {
                    float* C = (float*)Cbase + (size_t)z * strideCz;
                    float r2 = v + aux0[(size_t)gm * ldc + gn];
                    C[(size_t)gm * ldc + gn] = r2;
                    aux1[(size_t)gm * ldc + gn] = r2;
                } else if constexpr (EPI == EPI_F32) {
                    float* C = (float*)Cbase + (size_t)z * strideCz;
                    C[(size_t)gm * ldc + gn] = v;
                } else if constexpr (EPI == EPI_BF16) {
                    u16* C = (u16*)Cbase + (size_t)z * strideCz;
                    C[(size_t)gm * ldc + gn] = f2bf(v);
                } else if constexpr (EPI == EPI_SILUMUL) {
                    float tv = aux0[(size_t)z * strideAux + (size_t)gm * ldc + gn];
                    float sl = tv / (1.f + expf(-tv));
                    u16* C = (u16*)Cbase + (size_t)z * strideCz;
                    C[(size_t)gm * ldc + gn] = f2bf(sl * v);
                } else { // EPI_SCATTER
                    int tok = out_idx[(size_t)z * S + gm];
                    float g = gatesb[(size_t)z * S + gm];
                    atomicAdd((float*)Cbase + (size_t)tok * ldc + gn, g * v);
                }
            }
        }
    }
}

// ---------------------------------------------------------------------------
__global__ __launch_bounds__(256) void ln_kernel(
    const float* __restrict__ x, const float* __restrict__ w,
    u16* __restrict__ obf, float* __restrict__ of32)
{
    const int t = blockIdx.x;
    const float* xr = x + (size_t)t * DM;
    __shared__ float red[256];
    float vals[8];
    float s = 0.f, s2 = 0.f;
    for (int i = 0; i < 8; i++) {
        float v = xr[threadIdx.x + i * 256];
        vals[i] = v; s += v; s2 += v * v;
    }
    red[threadIdx.x] = s; __syncthreads();
    for (int st = 128; st > 0; st >>= 1) {
        if (threadIdx.x < st) red[threadIdx.x] += red[threadIdx.x + st];
        __syncthreads();
    }
    float mean = red[0] / DM; __syncthreads();
    red[threadIdx.x] = s2; __syncthreads();
    for (int st = 128; st > 0; st >>= 1) {
        if (threadIdx.x < st) red[threadIdx.x] += red[threadIdx.x + st];
        __syncthreads();
    }
    float var = red[0] / DM - mean * mean;
    float inv = 1.0f / sqrtf(var + 1e-5f);
    for (int i = 0; i < 8; i++) {
        int d = threadIdx.x + i * 256;
        float v = (vals[i] - mean) * inv * w[d];
        obf[(size_t)t * DM + d] = f2bf(v);
        if (of32) of32[(size_t)t * DM + d] = v;
    }
}

__global__ __launch_bounds__(256) void rope_kernel(
    const float* __restrict__ qkv, const int* __restrict__ pos_ids,
    u16* __restrict__ qb, u16* __restrict__ kb)
{
    int id = blockIdx.x * 256 + threadIdx.x;
    if (id >= S * (NH + NKV) * 64) return;
    int i = id & 63;
    int hh = (id >> 6) % (NH + NKV);
    int t = id / ((NH + NKV) * 64);
    float pos = (float)pos_ids[t];
    float invf = powf(500000.0f, -(float)i / 64.0f);
    float f = pos * invf;
    float c = cosf(f), sn = sinf(f);
    const float* base;
    u16* out;
    if (hh < NH) {
        base = qkv + (size_t)t * QKVN + hh * HD;
        out = qb + ((size_t)t * NH + hh) * HD;
    } else {
        int hk = hh - NH;
        base = qkv + (size_t)t * QKVN + DM + hk * HD;
        out = kb + ((size_t)t * NKV + hk) * HD;
    }
    float x1 = base[i], x2 = base[i + 64];
    out[i]      = f2bf(x1 * c - x2 * sn);
    out[i + 64] = f2bf(x2 * c + x1 * sn);
}

__global__ __launch_bounds__(256) void vconv_kernel(
    const float* __restrict__ qkv, u16* __restrict__ vb)
{
    int id = blockIdx.x * 256 + threadIdx.x;
    if (id >= S * NKV * HD) return;
    int t = id >> 9, c = id & 511;
    vb[id] = f2bf(qkv[(size_t)t * QKVN + DM + NKV * HD + c]);
}

__global__ __launch_bounds__(256) void softmax_kernel(
    const float* __restrict__ scores, u16* __restrict__ probs)
{
    const size_t row = blockIdx.x;
    const float* sr = scores + row * S;
    u16* pr = probs + row * S;
    __shared__ float red[256];
    float v[4];
    float m = -3.4e38f;
    for (int i = 0; i < 4; i++) {
        v[i] = sr[threadIdx.x + i * 256];
        m = fmaxf(m, v[i]);
    }
    red[threadIdx.x] = m; __syncthreads();
    for (int st = 128; st > 0; st >>= 1) {
        if (threadIdx.x < st) red[threadIdx.x] = fmaxf(red[threadIdx.x], red[threadIdx.x + st]);
        __syncthreads();
    }
    m = red[0]; __syncthreads();
    float ssum = 0.f; float e[4];
    for (int i = 0; i < 4; i++) { e[i] = expf(v[i] - m); ssum += e[i]; }
    red[threadIdx.x] = ssum; __syncthreads();
    for (int st = 128; st > 0; st >>= 1) {
        if (threadIdx.x < st) red[threadIdx.x] += red[threadIdx.x + st];
        __syncthreads();
    }
    float invl = 1.0f / red[0];
    for (int i = 0; i < 4; i++)
        pr[threadIdx.x + i * 256] = f2bf(e[i] * invl);
}

__global__ void zero_cnt_kernel(int* cnt) {
    if (threadIdx.x < NE) cnt[threadIdx.x] = 0;
}

__global__ __launch_bounds__(64) void router_kernel(
    const float* __restrict__ h2f, const float* __restrict__ rw,
    int* __restrict__ cnt, int* __restrict__ list, float* __restrict__ gates)
{
    const int t = blockIdx.x;
    const int l = threadIdx.x;
    const int e = l >> 3, p = l & 7;
    const float* hr = h2f + (size_t)t * DM;
    float s = 0.f;
    for (int d = p; d < DM; d += 8) s += hr[d] * rw[d * NE + e];
    s += __shfl_xor(s, 1);
    s += __shfl_xor(s, 2);
    s += __shfl_xor(s, 4);
    __shared__ float lg[NE];
    if (p == 0) lg[e] = s;
    __syncthreads();
    if (l == 0) {
        int e0 = 0; float m0 = lg[0];
        for (int q = 1; q < NE; q++) if (lg[q] > m0) { m0 = lg[q]; e0 = q; }
        int e1 = -1; float m1 = -3.4e38f;
        for (int q = 0; q < NE; q++) if (q != e0 && lg[q] > m1) { m1 = lg[q]; e1 = q; }
        float g0 = 1.0f / (1.0f + expf(m1 - m0));
        float g1 = 1.0f - g0;
        int p0 = atomicAdd(&cnt[e0], 1); list[e0 * S + p0] = t; gates[e0 * S + p0] = g0;
        int p1 = atomicAdd(&cnt[e1], 1); list[e1 * S + p1] = t; gates[e1 * S + p1] = g1;
    }
}

// ---------------------------------------------------------------------------
extern "C" void kernel_launch(void* const* d_in, const int* in_sizes, int n_in,
                              void* d_out, int out_size, void* d_ws, size_t ws_size,
                              hipStream_t stream)
{
    (void)in_sizes; (void)n_in; (void)out_size; (void)ws_size;
    const float* x     = (const float*)d_in[0];
    const int*   amask = (const int*)d_in[1];
    const int*   pos   = (const int*)d_in[2];
    const float* n1w   = (const float*)d_in[3];
    const float* n2w   = (const float*)d_in[4];
    const float* wqkv  = (const float*)d_in[5];
    const float* wout  = (const float*)d_in[6];
    const float* rw    = (const float*)d_in[7];
    const float* w1    = (const float*)d_in[8];
    const float* v1    = (const float*)d_in[9];
    const float* w2    = (const float*)d_in[10];
    float* out = (float*)d_out;

    char* p = (char*)d_ws;
    auto alloc = [&](size_t bytes) {
        char* r = p;
        p += (bytes + 255) & ~(size_t)255;
        return r;
    };
    float* resid = (float*)alloc((size_t)S * DM * 4);
    float* h2f   = (float*)alloc((size_t)S * DM * 4);
    u16*   h2b   = (u16*)alloc((size_t)S * DM * 2);
    u16*   h1b   = (u16*)alloc((size_t)S * DM * 2);
    u16*   qb    = (u16*)alloc((size_t)S * NH * HD * 2);
    u16*   kb    = (u16*)alloc((size_t)S * NKV * HD * 2);
    u16*   vb    = (u16*)alloc((size_t)S * NKV * HD * 2);
    u16*   attnb = (u16*)alloc((size_t)S * DM * 2);
    int*   cnt   = (int*)alloc(NE * 4);
    int*   list  = (int*)alloc((size_t)NE * S * 4);
    float* gates = (float*)alloc((size_t)NE * S * 4);
    float* qkv   = (float*)alloc((size_t)S * QKVN * 4);
    char*  arena = alloc((size_t)NH * S * S * 4 + (size_t)NH * S * S * 2); // 96 MiB
    float* scores = (float*)arena;
    u16*   probs  = (u16*)(arena + (size_t)NH * S * S * 4);
    float* t1 = (float*)arena;                                   // reuse (64 MiB <= 64 MiB)
    u16*   xx = (u16*)(arena + (size_t)NH * S * S * 4);          // reuse (32 MiB <= 32 MiB)

    // 1. LN1
    ln_kernel<<<S, 256, 0, stream>>>(x, n1w, h1b, nullptr);
    // 2. QKV = clip(h1 @ wqkv)
    gemm_kernel<BL_KN_F32, EPI_CLIP, false><<<dim3(QKVN / 128, S / 128, 1), 256, 0, stream>>>(
        h1b, DM, 0, wqkv, QKVN, 0, 1, qkv, QKVN, 0, S, DM,
        nullptr, nullptr, nullptr, nullptr, nullptr, 0, nullptr, nullptr);
    // 3. RoPE q,k ; 4. v convert
    rope_kernel<<<(S * (NH + NKV) * 64) / 256, 256, 0, stream>>>(qkv, pos, qb, kb);
    vconv_kernel<<<(S * NKV * HD) / 256, 256, 0, stream>>>(qkv, vb);
    // 5. scores = Q@K^T / sqrt(HD) with causal+attn mask (per head)
    gemm_kernel<BL_NK_BF16, EPI_SCORES, false><<<dim3(S / 128, S / 128, NH), 256, 0, stream>>>(
        qb, NH * HD, HD, kb, NKV * HD, HD, NH / NKV, scores, S, (long)S * S, S, HD,
        nullptr, nullptr, nullptr, nullptr, nullptr, 0, nullptr, amask);
    // 6. softmax rows -> probs (bf16)
    softmax_kernel<<<NH * S, 256, 0, stream>>>(scores, probs);
    // 7. attn = P @ V  (causal K-limit)
    gemm_kernel<BL_KN_BF16, EPI_BF16, true><<<dim3(HD / 128, S / 128, NH), 256, 0, stream>>>(
        probs, S, (long)S * S, vb, NKV * HD, HD, NH / NKV, attnb, DM, HD, S, S,
        nullptr, nullptr, nullptr, nullptr, nullptr, 0, nullptr, nullptr);
    // 8. resid = x + attn @ wout ; also init d_out = resid
    gemm_kernel<BL_KN_F32, EPI_RESID, false><<<dim3(DM / 128, S / 128, 1), 256, 0, stream>>>(
        attnb, DM, 0, wout, DM, 0, 1, resid, DM, 0, S, DM,
        nullptr, nullptr, nullptr, nullptr, x, 0, out, nullptr);
    // 9. LN2
    ln_kernel<<<S, 256, 0, stream>>>(resid, n2w, h2b, h2f);
    // 10/11. router
    zero_cnt_kernel<<<1, 64, 0, stream>>>(cnt);
    router_kernel<<<S, 64, 0, stream>>>(h2f, rw, cnt, list, gates);
    // 12. t1 = gathered h2 @ w1[e]^T   (z = expert)
    gemm_kernel<BL_NK_F32, EPI_F32, false><<<dim3(FF / 128, S / 128, NE), 256, 0, stream>>>(
        h2b, DM, 0, w1, DM, (long)FF * DM, 1, t1, FF, (long)S * FF, S, DM,
        list, nullptr, nullptr, cnt, nullptr, 0, nullptr, nullptr);
    // 13. xx = silu(t1) * (gathered h2 @ v1[e]^T)
    gemm_kernel<BL_NK_F32, EPI_SILUMUL, false><<<dim3(FF / 128, S / 128, NE), 256, 0, stream>>>(
        h2b, DM, 0, v1, DM, (long)FF * DM, 1, xx, FF, (long)S * FF, S, DM,
        list, nullptr, nullptr, cnt, t1, (long)S * FF, nullptr, nullptr);
    // 14. d_out[token] += gate * (xx @ w2[e])
    gemm_kernel<BL_KN_F32, EPI_SCATTER, false><<<dim3(DM / 128, S / 128, NE), 256, 0, stream>>>(
        xx, FF, (long)S * FF, w2, DM, (long)FF * DM, 1, out, DM, 0, S, FF,
        nullptr, list, gates, cnt, nullptr, 0, nullptr, nullptr);
}

// Round 2
// 929.055 us; speedup vs baseline: 2.0216x; 2.0216x over previous
//
#include <hip/hip_runtime.h>
#include <math.h>

#define S 1024
#define DM 2048
#define NH 16
#define NKV 4
#define HD 128
#define NE 8
#define FF 2048
#define QKVN 3072

typedef float f32x4 __attribute__((ext_vector_type(4)));
typedef short bf16x8 __attribute__((ext_vector_type(8)));
typedef unsigned short u16;

__device__ __forceinline__ u16 f2bf(float x) {
    union { float f; unsigned u; } v; v.f = x;
    unsigned r = v.u + 0x7FFFu + ((v.u >> 16) & 1u);
    return (u16)(r >> 16);
}

// async global->LDS, 16B per lane; LDS dest is wave-uniform base + lane*16
__device__ __forceinline__ void gl_lds16(const u16* g, u16* l) {
    __builtin_amdgcn_global_load_lds(
        (const __attribute__((address_space(1))) void*)g,
        (__attribute__((address_space(3))) void*)l, 16, 0, 0);
}

enum { EPI_CLIP = 0, EPI_RESID = 1, EPI_SCORES = 2, EPI_BF16 = 3, EPI_F32 = 4,
       EPI_SILUMUL = 5, EPI_SCATTER = 6 };

// ---------------------------------------------------------------------------
// m97-style GEMM: tile 64(M) x 128(N), BK=32, 4 waves (2x2, each 32x64 as
// 2x4 MFMA 16x16x32 tiles).  A: bf16 MxK row-major (optional row gather).
// B: bf16 NxK row-major ("B^T").  Staging via global_load_lds width 16 into
// unpadded LDS [rows][32] (64B row stride -> 2-way bank alias = free).
// ---------------------------------------------------------------------------
template<int EPI, bool KLIM, bool GATHER>
__global__ __launch_bounds__(256) void gemm_kernel(
    const u16* __restrict__ Abase, long lda, long strideAz,
    const u16* __restrict__ Bbase, long ldb, long strideBz, int zdivB,
    void* __restrict__ Cbase, long ldc, long strideCz,
    int M, int K,
    const int* __restrict__ a_idx,     // per-z stride S (A row remap)
    const int* __restrict__ out_idx,   // per-z stride S (C row scatter)
    const float* __restrict__ gatesb,  // per-z stride S
    const int* __restrict__ cntp,      // per-z M override
    const float* __restrict__ aux0, long strideAux,
    float* __restrict__ aux1,
    const int* __restrict__ amask)
{
    const int z = blockIdx.z;
    int Mz = M;
    if (cntp) Mz = cntp[z];
    const int bm = blockIdx.y, bn = blockIdx.x;
    if (bm * 64 >= Mz) return;

    const int tid = threadIdx.x;
    const int lane = tid & 63, wave = tid >> 6;
    const int ln = lane & 15, quad = lane >> 4;
    const int wm = wave >> 1, wn = wave & 1;

    float* Cz = (float*)Cbase + (size_t)z * strideCz;

    // fully-masked causal score tiles: fill and exit
    if (EPI == EPI_SCORES && bn * 128 >= bm * 64 + 64) {
        const float4 mv = make_float4(-3.0e38f, -3.0e38f, -3.0e38f, -3.0e38f);
        for (int t = tid; t < 64 * 32; t += 256) {
            int row = t >> 5, c4 = (t & 31) * 4;
            *(float4*)&Cz[(size_t)(bm * 64 + row) * ldc + bn * 128 + c4] = mv;
        }
        return;
    }

    __shared__ u16 lA[64 * 32];    // 4 KiB
    __shared__ u16 lB[128 * 32];   // 8 KiB

    const u16* A = Abase + (size_t)z * strideAz;
    const u16* B = Bbase + (size_t)(z / zdivB) * strideBz;

    // loop-invariant per-lane source pointers (k0 added each step)
    const int am = bm * 64 + wave * 16 + (lane >> 2);
    long arow;
    if (GATHER) arow = (am < Mz) ? (long)a_idx[(size_t)z * S + am] : 0;
    else        arow = (am < Mz) ? (long)am : 0;
    const u16* aptr  = A + arow * lda + (lane & 3) * 8;
    const int bn0 = bn * 128 + wave * 32 + (lane >> 2);
    const u16* bptr0 = B + (size_t)bn0 * ldb + (lane & 3) * 8;
    const u16* bptr1 = bptr0 + (size_t)16 * ldb;
    u16* lAw  = lA + wave * 512;    // wave-uniform LDS bases
    u16* lBw0 = lB + wave * 1024;
    u16* lBw1 = lBw0 + 512;

    f32x4 acc[2][4];
#pragma unroll
    for (int i = 0; i < 2; i++)
#pragma unroll
        for (int j = 0; j < 4; j++)
            acc[i][j] = (f32x4){0.f, 0.f, 0.f, 0.f};

    const int kcap = bm * 64 + 64;
    const int kmax = KLIM ? ((K < kcap) ? K : kcap) : K;

    for (int k0 = 0; k0 < kmax; k0 += 32) {
        __syncthreads();
        gl_lds16(aptr + k0, lAw);
        gl_lds16(bptr0 + k0, lBw0);
        gl_lds16(bptr1 + k0, lBw1);
        __syncthreads();
        bf16x8 af[2], bfr[4];
#pragma unroll
        for (int i = 0; i < 2; i++)
            af[i] = *(const bf16x8*)&lA[(wm * 32 + i * 16 + ln) * 32 + quad * 8];
#pragma unroll
        for (int j = 0; j < 4; j++)
            bfr[j] = *(const bf16x8*)&lB[(wn * 64 + j * 16 + ln) * 32 + quad * 8];
#pragma unroll
        for (int i = 0; i < 2; i++)
#pragma unroll
            for (int j = 0; j < 4; j++)
                acc[i][j] = __builtin_amdgcn_mfma_f32_16x16x32_bf16(af[i], bfr[j], acc[i][j], 0, 0, 0);
    }

    // epilogue: D row = quad*4 + reg, col = ln
    const int baserow = bm * 64 + wm * 32;
    const int basecol = bn * 128 + wn * 64;
#pragma unroll
    for (int i = 0; i < 2; i++) {
#pragma unroll
        for (int j = 0; j < 4; j++) {
#pragma unroll
            for (int r = 0; r < 4; r++) {
                int gm = baserow + i * 16 + quad * 4 + r;
                int gn = basecol + j * 16 + ln;
                if (gm >= Mz) continue;
                float v = acc[i][j][r];
                if constexpr (EPI == EPI_CLIP) {
                    Cz[(size_t)gm * ldc + gn] = fminf(fmaxf(v, -8.f), 8.f);
                } else if constexpr (EPI == EPI_SCORES) {
                    float sv = v * 0.08838834764831845f;
                    if (gn > gm || amask[gn] == 0) sv = -3.0e38f;
                    Cz[(size_t)gm * ldc + gn] = sv;
                } else if constexpr (EPI == EPI_RESID) {
                    float r2 = v + aux0[(size_t)gm * ldc + gn];
                    Cz[(size_t)gm * ldc + gn] = r2;
                    aux1[(size_t)gm * ldc + gn] = r2;
                } else if constexpr (EPI == EPI_F32) {
                    Cz[(size_t)gm * ldc + gn] = v;
                } else if constexpr (EPI == EPI_BF16) {
                    u16* C = (u16*)Cbase + (size_t)z * strideCz;
                    C[(size_t)gm * ldc + gn] = f2bf(v);
                } else if constexpr (EPI == EPI_SILUMUL) {
                    float tv = aux0[(size_t)z * strideAux + (size_t)gm * ldc + gn];
                    float sl = tv / (1.f + expf(-tv));
                    u16* C = (u16*)Cbase + (size_t)z * strideCz;
                    C[(size_t)gm * ldc + gn] = f2bf(sl * v);
                } else { // EPI_SCATTER
                    int tok = out_idx[(size_t)z * S + gm];
                    float g = gatesb[(size_t)z * S + gm];
                    atomicAdd((float*)Cbase + (size_t)tok * ldc + gn, g * v);
                }
            }
        }
    }
}

// ---------------------------------------------------------------------------
// f32 -> bf16 straight cast (w1, v1)
__global__ __launch_bounds__(256) void cvt_kernel(
    const float* __restrict__ s, u16* __restrict__ d, long n)
{
    long i = ((long)blockIdx.x * 256 + threadIdx.x) * 8;
    if (i >= n) return;
    float4 a = *(const float4*)(s + i);
    float4 b = *(const float4*)(s + i + 4);
    u16 o[8] = { f2bf(a.x), f2bf(a.y), f2bf(a.z), f2bf(a.w),
                 f2bf(b.x), f2bf(b.y), f2bf(b.z), f2bf(b.w) };
    *(uint4*)(d + i) = *(uint4*)o;
}

// f32 RxC (ld=ldsrc) -> bf16 CxR (ld=lddst), 32x32 LDS tiles
__global__ __launch_bounds__(256) void transpose_kernel(
    const float* __restrict__ src, long ldsrc, long srcZ,
    u16* __restrict__ dst, long lddst, long dstZ)
{
    __shared__ u16 t[32][33];
    const float* s = src + (size_t)blockIdx.z * srcZ;
    u16* d = dst + (size_t)blockIdx.z * dstZ;
    int c0 = blockIdx.x * 32, r0 = blockIdx.y * 32;
    int tx = threadIdx.x & 31, ty = threadIdx.x >> 5;
#pragma unroll
    for (int i = 0; i < 32; i += 8)
        t[ty + i][tx] = f2bf(s[(size_t)(r0 + ty + i) * ldsrc + c0 + tx]);
    __syncthreads();
#pragma unroll
    for (int i = 0; i < 32; i += 8)
        d[(size_t)(c0 + ty + i) * lddst + r0 + tx] = t[tx][ty + i];
}

// ---------------------------------------------------------------------------
__global__ __launch_bounds__(256) void ln_kernel(
    const float* __restrict__ x, const float* __restrict__ w,
    u16* __restrict__ obf, float* __restrict__ of32)
{
    const int t = blockIdx.x;
    const float* xr = x + (size_t)t * DM;
    __shared__ float red[256];
    float vals[8];
    float s = 0.f, s2 = 0.f;
    for (int i = 0; i < 8; i++) {
        float v = xr[threadIdx.x + i * 256];
        vals[i] = v; s += v; s2 += v * v;
    }
    red[threadIdx.x] = s; __syncthreads();
    for (int st = 128; st > 0; st >>= 1) {
        if (threadIdx.x < st) red[threadIdx.x] += red[threadIdx.x + st];
        __syncthreads();
    }
    float mean = red[0] / DM; __syncthreads();
    red[threadIdx.x] = s2; __syncthreads();
    for (int st = 128; st > 0; st >>= 1) {
        if (threadIdx.x < st) red[threadIdx.x] += red[threadIdx.x + st];
        __syncthreads();
    }
    float var = red[0] / DM - mean * mean;
    float inv = 1.0f / sqrtf(var + 1e-5f);
    for (int i = 0; i < 8; i++) {
        int d = threadIdx.x + i * 256;
        float v = (vals[i] - mean) * inv * w[d];
        obf[(size_t)t * DM + d] = f2bf(v);
        if (of32) of32[(size_t)t * DM + d] = v;
    }
}

__global__ __launch_bounds__(256) void rope_kernel(
    const float* __restrict__ qkv, const int* __restrict__ pos_ids,
    u16* __restrict__ qb, u16* __restrict__ kb)
{
    int id = blockIdx.x * 256 + threadIdx.x;
    if (id >= S * (NH + NKV) * 64) return;
    int i = id & 63;
    int hh = (id >> 6) % (NH + NKV);
    int t = id / ((NH + NKV) * 64);
    float pos = (float)pos_ids[t];
    float invf = powf(500000.0f, -(float)i / 64.0f);
    float f = pos * invf;
    float c = cosf(f), sn = sinf(f);
    const float* base;
    u16* out;
    if (hh < NH) {
        base = qkv + (size_t)t * QKVN + hh * HD;
        out = qb + ((size_t)t * NH + hh) * HD;
    } else {
        int hk = hh - NH;
        base = qkv + (size_t)t * QKVN + DM + hk * HD;
        out = kb + ((size_t)t * NKV + hk) * HD;
    }
    float x1 = base[i], x2 = base[i + 64];
    out[i]      = f2bf(x1 * c - x2 * sn);
    out[i + 64] = f2bf(x2 * c + x1 * sn);
}

__global__ __launch_bounds__(256) void softmax_kernel(
    const float* __restrict__ scores, u16* __restrict__ probs)
{
    const size_t row = blockIdx.x;
    const float* sr = scores + row * S;
    u16* pr = probs + row * S;
    __shared__ float red[256];
    float v[4];
    float m = -3.4e38f;
    for (int i = 0; i < 4; i++) {
        v[i] = sr[threadIdx.x + i * 256];
        m = fmaxf(m, v[i]);
    }
    red[threadIdx.x] = m; __syncthreads();
    for (int st = 128; st > 0; st >>= 1) {
        if (threadIdx.x < st) red[threadIdx.x] = fmaxf(red[threadIdx.x], red[threadIdx.x + st]);
        __syncthreads();
    }
    m = red[0]; __syncthreads();
    float ssum = 0.f; float e[4];
    for (int i = 0; i < 4; i++) { e[i] = expf(v[i] - m); ssum += e[i]; }
    red[threadIdx.x] = ssum; __syncthreads();
    for (int st = 128; st > 0; st >>= 1) {
        if (threadIdx.x < st) red[threadIdx.x] += red[threadIdx.x + st];
        __syncthreads();
    }
    float invl = 1.0f / red[0];
    for (int i = 0; i < 4; i++)
        pr[threadIdx.x + i * 256] = f2bf(e[i] * invl);
}

__global__ void zero_cnt_kernel(int* cnt) {
    if (threadIdx.x < NE) cnt[threadIdx.x] = 0;
}

__global__ __launch_bounds__(64) void router_kernel(
    const float* __restrict__ h2f, const float* __restrict__ rw,
    int* __restrict__ cnt, int* __restrict__ list, float* __restrict__ gates)
{
    const int t = blockIdx.x;
    const int l = threadIdx.x;
    const int e = l >> 3, p = l & 7;
    const float* hr = h2f + (size_t)t * DM;
    float s = 0.f;
    for (int d = p; d < DM; d += 8) s += hr[d] * rw[d * NE + e];
    s += __shfl_xor(s, 1);
    s += __shfl_xor(s, 2);
    s += __shfl_xor(s, 4);
    __shared__ float lg[NE];
    if (p == 0) lg[e] = s;
    __syncthreads();
    if (l == 0) {
        int e0 = 0; float m0 = lg[0];
        for (int q = 1; q < NE; q++) if (lg[q] > m0) { m0 = lg[q]; e0 = q; }
        int e1 = -1; float m1 = -3.4e38f;
        for (int q = 0; q < NE; q++) if (q != e0 && lg[q] > m1) { m1 = lg[q]; e1 = q; }
        float g0 = 1.0f / (1.0f + expf(m1 - m0));
        float g1 = 1.0f - g0;
        int p0 = atomicAdd(&cnt[e0], 1); list[e0 * S + p0] = t; gates[e0 * S + p0] = g0;
        int p1 = atomicAdd(&cnt[e1], 1); list[e1 * S + p1] = t; gates[e1 * S + p1] = g1;
    }
}

// ---------------------------------------------------------------------------
extern "C" void kernel_launch(void* const* d_in, const int* in_sizes, int n_in,
                              void* d_out, int out_size, void* d_ws, size_t ws_size,
                              hipStream_t stream)
{
    (void)in_sizes; (void)n_in; (void)out_size; (void)ws_size;
    const float* x     = (const float*)d_in[0];
    const int*   amask = (const int*)d_in[1];
    const int*   pos   = (const int*)d_in[2];
    const float* n1w   = (const float*)d_in[3];
    const float* n2w   = (const float*)d_in[4];
    const float* wqkv  = (const float*)d_in[5];
    const float* wout  = (const float*)d_in[6];
    const float* rw    = (const float*)d_in[7];
    const float* w1    = (const float*)d_in[8];
    const float* v1    = (const float*)d_in[9];
    const float* w2    = (const float*)d_in[10];
    float* out = (float*)d_out;

    char* p = (char*)d_ws;
    auto alloc = [&](size_t bytes) {
        char* r = p;
        p += (bytes + 255) & ~(size_t)255;
        return r;
    };
    float* resid  = (float*)alloc((size_t)S * DM * 4);
    float* h2f    = (float*)alloc((size_t)S * DM * 4);
    u16*   h2b    = (u16*)alloc((size_t)S * DM * 2);
    u16*   h1b    = (u16*)alloc((size_t)S * DM * 2);
    u16*   qb     = (u16*)alloc((size_t)S * NH * HD * 2);
    u16*   kb     = (u16*)alloc((size_t)S * NKV * HD * 2);
    u16*   vT     = (u16*)alloc((size_t)NKV * HD * S * 2);
    u16*   attnb  = (u16*)alloc((size_t)S * DM * 2);
    int*   cnt    = (int*)alloc(NE * 4);
    int*   list   = (int*)alloc((size_t)NE * S * 4);
    float* gates  = (float*)alloc((size_t)NE * S * 4);
    float* qkv    = (float*)alloc((size_t)S * QKVN * 4);
    u16*   wqkvT  = (u16*)alloc((size_t)QKVN * DM * 2);
    u16*   woutT  = (u16*)alloc((size_t)DM * DM * 2);
    u16*   wb     = (u16*)alloc((size_t)NE * FF * DM * 2);   // shared MoE weight buf (67MB)
    char*  arena  = alloc((size_t)NH * S * S * 4 + (size_t)NH * S * S * 2); // 96 MiB
    float* scores = (float*)arena;
    u16*   probs  = (u16*)(arena + (size_t)NH * S * S * 4);
    float* t1 = (float*)arena;                               // reuse after attention
    u16*   xx = (u16*)(arena + (size_t)NH * S * S * 4);

    // weight pre-pass: wqkv (K x N) -> bf16 N x K ; wout likewise
    transpose_kernel<<<dim3(QKVN / 32, DM / 32, 1), 256, 0, stream>>>(
        wqkv, QKVN, 0, wqkvT, DM, 0);
    transpose_kernel<<<dim3(DM / 32, DM / 32, 1), 256, 0, stream>>>(
        wout, DM, 0, woutT, DM, 0);

    // 1. LN1
    ln_kernel<<<S, 256, 0, stream>>>(x, n1w, h1b, nullptr);
    // 2. QKV = clip(h1 @ wqkv)
    gemm_kernel<EPI_CLIP, false, false><<<dim3(QKVN / 128, S / 64, 1), 256, 0, stream>>>(
        h1b, DM, 0, wqkvT, DM, 0, 1, qkv, QKVN, 0, S, DM,
        nullptr, nullptr, nullptr, nullptr, nullptr, 0, nullptr, nullptr);
    // 3. RoPE q,k ; V^T (bf16, [NKV][HD][S])
    rope_kernel<<<(S * (NH + NKV) * 64) / 256, 256, 0, stream>>>(qkv, pos, qb, kb);
    transpose_kernel<<<dim3((NKV * HD) / 32, S / 32, 1), 256, 0, stream>>>(
        qkv + DM + NKV * HD, QKVN, 0, vT, S, 0);
    // 5. scores = Q@K^T/sqrt(HD), causal+mask
    gemm_kernel<EPI_SCORES, false, false><<<dim3(S / 128, S / 64, NH), 256, 0, stream>>>(
        qb, NH * HD, HD, kb, NKV * HD, HD, NH / NKV, scores, S, (long)S * S, S, HD,
        nullptr, nullptr, nullptr, nullptr, nullptr, 0, nullptr, amask);
    // 6. softmax
    softmax_kernel<<<NH * S, 256, 0, stream>>>(scores, probs);
    // 7. attn = P @ V (causal K-limit)
    gemm_kernel<EPI_BF16, true, false><<<dim3(HD / 128, S / 64, NH), 256, 0, stream>>>(
        probs, S, (long)S * S, vT, S, (long)HD * S, NH / NKV, attnb, DM, HD, S, S,
        nullptr, nullptr, nullptr, nullptr, nullptr, 0, nullptr, nullptr);
    // 8. resid = x + attn @ wout ; d_out = resid
    gemm_kernel<EPI_RESID, false, false><<<dim3(DM / 128, S / 64, 1), 256, 0, stream>>>(
        attnb, DM, 0, woutT, DM, 0, 1, resid, DM, 0, S, DM,
        nullptr, nullptr, nullptr, nullptr, x, 0, out, nullptr);
    // 9. LN2
    ln_kernel<<<S, 256, 0, stream>>>(resid, n2w, h2b, h2f);
    // 10/11. router
    zero_cnt_kernel<<<1, 64, 0, stream>>>(cnt);
    router_kernel<<<S, 64, 0, stream>>>(h2f, rw, cnt, list, gates);
    // 12. t1 = gathered h2 @ w1[e]^T
    cvt_kernel<<<(int)(((long)NE * FF * DM / 8 + 255) / 256), 256, 0, stream>>>(
        w1, wb, (long)NE * FF * DM);
    gemm_kernel<EPI_F32, false, true><<<dim3(FF / 128, S / 64, NE), 256, 0, stream>>>(
        h2b, DM, 0, wb, DM, (long)FF * DM, 1, t1, FF, (long)S * FF, S, DM,
        list, nullptr, nullptr, cnt, nullptr, 0, nullptr, nullptr);
    // 13. xx = silu(t1) * (gathered h2 @ v1[e]^T)
    cvt_kernel<<<(int)(((long)NE * FF * DM / 8 + 255) / 256), 256, 0, stream>>>(
        v1, wb, (long)NE * FF * DM);
    gemm_kernel<EPI_SILUMUL, false, true><<<dim3(FF / 128, S / 64, NE), 256, 0, stream>>>(
        h2b, DM, 0, wb, DM, (long)FF * DM, 1, xx, FF, (long)S * FF, S, DM,
        list, nullptr, nullptr, cnt, t1, (long)S * FF, nullptr, nullptr);
    // 14. d_out[token] += gate * (xx @ w2[e])   (w2 F x D -> bf16 D x F)
    transpose_kernel<<<dim3(DM / 32, FF / 32, NE), 256, 0, stream>>>(
        w2, DM, (long)FF * DM, wb, FF, (long)DM * FF);
    gemm_kernel<EPI_SCATTER, false, false><<<dim3(DM / 128, S / 64, NE), 256, 0, stream>>>(
        xx, FF, (long)S * FF, wb, FF, (long)DM * FF, 1, out, DM, 0, S, FF,
        nullptr, list, gates, cnt, nullptr, 0, nullptr, nullptr);
}

// Round 3
// 871.634 us; speedup vs baseline: 2.1547x; 1.0659x over previous
//
#include <hip/hip_runtime.h>
#include <math.h>

#define S 1024
#define DM 2048
#define NH 16
#define NKV 4
#define HD 128
#define NE 8
#define FF 2048
#define QKVN 3072

typedef float f32x4 __attribute__((ext_vector_type(4)));
typedef short bf16x8 __attribute__((ext_vector_type(8)));
typedef unsigned short u16;

__device__ __forceinline__ u16 f2bf(float x) {
    union { float f; unsigned u; } v; v.f = x;
    unsigned r = v.u + 0x7FFFu + ((v.u >> 16) & 1u);
    return (u16)(r >> 16);
}

// async global->LDS, 16B per lane; LDS dest is wave-uniform base + lane*16
__device__ __forceinline__ void gl_lds16(const u16* g, u16* l) {
    __builtin_amdgcn_global_load_lds(
        (const __attribute__((address_space(1))) void*)g,
        (__attribute__((address_space(3))) void*)l, 16, 0, 0);
}

enum { EPI_CLIP = 0, EPI_RESID = 1, EPI_SCORES = 2, EPI_BF16 = 3, EPI_F32 = 4,
       EPI_SILUMUL = 5, EPI_SCATTER = 6 };

// ---------------------------------------------------------------------------
// 64(M) x 128(N) tile, BK=32, double-buffered LDS via global_load_lds.
// 4 waves (2x2), each wave 32x64 = 2x4 MFMA 16x16x32 tiles.
// A: bf16 MxK row-major (optional row gather).  B: bf16 NxK row-major.
// ---------------------------------------------------------------------------
template<int EPI, bool KLIM, bool GATHER>
__global__ __launch_bounds__(256) void gemm_kernel(
    const u16* __restrict__ Abase, long lda, long strideAz,
    const u16* __restrict__ Bbase, long ldb, long strideBz, int zdivB,
    void* __restrict__ Cbase, long ldc, long strideCz,
    int M, int K,
    const int* __restrict__ a_idx,     // per-z stride S (A row remap)
    const int* __restrict__ out_idx,   // per-z stride S (C row scatter)
    const float* __restrict__ gatesb,  // per-z stride S
    const int* __restrict__ cntp,      // per-z M override
    const float* __restrict__ aux0, long strideAux,
    float* __restrict__ aux1,
    const int* __restrict__ amask)
{
    const int z = blockIdx.z;
    int Mz = M;
    if (cntp) Mz = cntp[z];
    const int bm = blockIdx.y, bn = blockIdx.x;
    if (bm * 64 >= Mz) return;
    // fully-masked causal score tiles: nothing to do (softmax is span-aware)
    if (EPI == EPI_SCORES && bn * 128 >= bm * 64 + 64) return;

    const int tid = threadIdx.x;
    const int lane = tid & 63, wave = tid >> 6;
    const int ln = lane & 15, quad = lane >> 4;
    const int wm = wave >> 1, wn = wave & 1;

    float* Cz = (float*)Cbase + (size_t)z * strideCz;

    __shared__ u16 lA[2 * 64 * 32];    // 8 KiB
    __shared__ u16 lB[2 * 128 * 32];   // 16 KiB

    const u16* A = Abase + (size_t)z * strideAz;
    const u16* B = Bbase + (size_t)(z / zdivB) * strideBz;

    // loop-invariant per-lane source pointers (k0 added each step)
    const int am = bm * 64 + wave * 16 + (lane >> 2);
    long arow;
    if (GATHER) arow = (am < Mz) ? (long)a_idx[(size_t)z * S + am] : 0;
    else        arow = (am < Mz) ? (long)am : 0;
    const u16* aptr  = A + arow * lda + (lane & 3) * 8;
    const int bn0 = bn * 128 + wave * 32 + (lane >> 2);
    const u16* bptr0 = B + (size_t)bn0 * ldb + (lane & 3) * 8;
    const u16* bptr1 = bptr0 + (size_t)16 * ldb;
    u16* lAw  = lA + wave * 512;    // wave-uniform LDS bases
    u16* lBw0 = lB + wave * 1024;
    u16* lBw1 = lBw0 + 512;

    f32x4 acc[2][4];
#pragma unroll
    for (int i = 0; i < 2; i++)
#pragma unroll
        for (int j = 0; j < 4; j++)
            acc[i][j] = (f32x4){0.f, 0.f, 0.f, 0.f};

    const int kcap = bm * 64 + 64;
    const int kmax = KLIM ? ((K < kcap) ? K : kcap) : K;

    // prologue: load k0=0 into buf 0
    gl_lds16(aptr, lAw);
    gl_lds16(bptr0, lBw0);
    gl_lds16(bptr1, lBw1);

    int buf = 0;
    for (int k0 = 0; k0 < kmax; k0 += 32) {
        __syncthreads();               // drains loads of current buf
        const int kn = k0 + 32;
        if (kn < kmax) {               // prefetch next K-slice into other buf
            const int nb = buf ^ 1;
            gl_lds16(aptr + kn, lAw + nb * 2048);
            gl_lds16(bptr0 + kn, lBw0 + nb * 4096);
            gl_lds16(bptr1 + kn, lBw1 + nb * 4096);
        }
        const u16* cA = lA + buf * 2048;
        const u16* cB = lB + buf * 4096;
        bf16x8 af[2], bfr[4];
#pragma unroll
        for (int i = 0; i < 2; i++)
            af[i] = *(const bf16x8*)&cA[(wm * 32 + i * 16 + ln) * 32 + quad * 8];
#pragma unroll
        for (int j = 0; j < 4; j++)
            bfr[j] = *(const bf16x8*)&cB[(wn * 64 + j * 16 + ln) * 32 + quad * 8];
#pragma unroll
        for (int i = 0; i < 2; i++)
#pragma unroll
            for (int j = 0; j < 4; j++)
                acc[i][j] = __builtin_amdgcn_mfma_f32_16x16x32_bf16(af[i], bfr[j], acc[i][j], 0, 0, 0);
        buf ^= 1;
    }

    // epilogue: D row = quad*4 + reg, col = ln
    const int baserow = bm * 64 + wm * 32;
    const int basecol = bn * 128 + wn * 64;
#pragma unroll
    for (int i = 0; i < 2; i++) {
#pragma unroll
        for (int j = 0; j < 4; j++) {
#pragma unroll
            for (int r = 0; r < 4; r++) {
                int gm = baserow + i * 16 + quad * 4 + r;
                int gn = basecol + j * 16 + ln;
                if (gm >= Mz) continue;
                float v = acc[i][j][r];
                if constexpr (EPI == EPI_CLIP) {
                    Cz[(size_t)gm * ldc + gn] = fminf(fmaxf(v, -8.f), 8.f);
                } else if constexpr (EPI == EPI_SCORES) {
                    float sv = v * 0.08838834764831845f;
                    if (gn > gm || amask[gn] == 0) sv = -3.0e38f;
                    Cz[(size_t)gm * ldc + gn] = sv;
                } else if constexpr (EPI == EPI_RESID) {
                    float r2 = v + aux0[(size_t)gm * ldc + gn];
                    Cz[(size_t)gm * ldc + gn] = r2;
                    aux1[(size_t)gm * ldc + gn] = r2;
                } else if constexpr (EPI == EPI_F32) {
                    Cz[(size_t)gm * ldc + gn] = v;
                } else if constexpr (EPI == EPI_BF16) {
                    u16* C = (u16*)Cbase + (size_t)z * strideCz;
                    C[(size_t)gm * ldc + gn] = f2bf(v);
                } else if constexpr (EPI == EPI_SILUMUL) {
                    float tv = aux0[(size_t)z * strideAux + (size_t)gm * ldc + gn];
                    float sl = tv / (1.f + expf(-tv));
                    u16* C = (u16*)Cbase + (size_t)z * strideCz;
                    C[(size_t)gm * ldc + gn] = f2bf(sl * v);
                } else { // EPI_SCATTER
                    int tok = out_idx[(size_t)z * S + gm];
                    float g = gatesb[(size_t)z * S + gm];
                    atomicAdd((float*)Cbase + (size_t)tok * ldc + gn, g * v);
                }
            }
        }
    }
}

// ---------------------------------------------------------------------------
// f32 -> bf16 straight cast (w1, v1)
__global__ __launch_bounds__(256) void cvt_kernel(
    const float* __restrict__ s, u16* __restrict__ d, long n)
{
    long i = ((long)blockIdx.x * 256 + threadIdx.x) * 8;
    if (i >= n) return;
    float4 a = *(const float4*)(s + i);
    float4 b = *(const float4*)(s + i + 4);
    u16 o[8] = { f2bf(a.x), f2bf(a.y), f2bf(a.z), f2bf(a.w),
                 f2bf(b.x), f2bf(b.y), f2bf(b.z), f2bf(b.w) };
    *(uint4*)(d + i) = *(uint4*)o;
}

// f32 RxC (ld=ldsrc) -> bf16 CxR (ld=lddst), 32x32 LDS tiles
__global__ __launch_bounds__(256) void transpose_kernel(
    const float* __restrict__ src, long ldsrc, long srcZ,
    u16* __restrict__ dst, long lddst, long dstZ)
{
    __shared__ u16 t[32][33];
    const float* s = src + (size_t)blockIdx.z * srcZ;
    u16* d = dst + (size_t)blockIdx.z * dstZ;
    int c0 = blockIdx.x * 32, r0 = blockIdx.y * 32;
    int tx = threadIdx.x & 31, ty = threadIdx.x >> 5;
#pragma unroll
    for (int i = 0; i < 32; i += 8)
        t[ty + i][tx] = f2bf(s[(size_t)(r0 + ty + i) * ldsrc + c0 + tx]);
    __syncthreads();
#pragma unroll
    for (int i = 0; i < 32; i += 8)
        d[(size_t)(c0 + ty + i) * lddst + r0 + tx] = t[tx][ty + i];
}

// ---------------------------------------------------------------------------
__global__ __launch_bounds__(256) void ln_kernel(
    const float* __restrict__ x, const float* __restrict__ w,
    u16* __restrict__ obf, float* __restrict__ of32, int* __restrict__ cnt0)
{
    const int t = blockIdx.x;
    if (cnt0 && t == 0 && threadIdx.x < NE) cnt0[threadIdx.x] = 0;
    const float* xr = x + (size_t)t * DM;
    __shared__ float red[256];
    float vals[8];
    float s = 0.f, s2 = 0.f;
    for (int i = 0; i < 8; i++) {
        float v = xr[threadIdx.x + i * 256];
        vals[i] = v; s += v; s2 += v * v;
    }
    red[threadIdx.x] = s; __syncthreads();
    for (int st = 128; st > 0; st >>= 1) {
        if (threadIdx.x < st) red[threadIdx.x] += red[threadIdx.x + st];
        __syncthreads();
    }
    float mean = red[0] / DM; __syncthreads();
    red[threadIdx.x] = s2; __syncthreads();
    for (int st = 128; st > 0; st >>= 1) {
        if (threadIdx.x < st) red[threadIdx.x] += red[threadIdx.x + st];
        __syncthreads();
    }
    float var = red[0] / DM - mean * mean;
    float inv = 1.0f / sqrtf(var + 1e-5f);
    for (int i = 0; i < 8; i++) {
        int d = threadIdx.x + i * 256;
        float v = (vals[i] - mean) * inv * w[d];
        obf[(size_t)t * DM + d] = f2bf(v);
        if (of32) of32[(size_t)t * DM + d] = v;
    }
}

__global__ __launch_bounds__(256) void rope_kernel(
    const float* __restrict__ qkv, const int* __restrict__ pos_ids,
    u16* __restrict__ qb, u16* __restrict__ kb)
{
    int id = blockIdx.x * 256 + threadIdx.x;
    if (id >= S * (NH + NKV) * 64) return;
    int i = id & 63;
    int hh = (id >> 6) % (NH + NKV);
    int t = id / ((NH + NKV) * 64);
    float pos = (float)pos_ids[t];
    float invf = powf(500000.0f, -(float)i / 64.0f);
    float f = pos * invf;
    float c = cosf(f), sn = sinf(f);
    const float* base;
    u16* out;
    if (hh < NH) {
        base = qkv + (size_t)t * QKVN + hh * HD;
        out = qb + ((size_t)t * NH + hh) * HD;
    } else {
        int hk = hh - NH;
        base = qkv + (size_t)t * QKVN + DM + hk * HD;
        out = kb + ((size_t)t * NKV + hk) * HD;
    }
    float x1 = base[i], x2 = base[i + 64];
    out[i]      = f2bf(x1 * c - x2 * sn);
    out[i + 64] = f2bf(x2 * c + x1 * sn);
}

// causal-span softmax: row r only reads/writes cols [0, NW) where
// NW = ceil128(tile_end) = the span the scores GEMM actually wrote.
__global__ __launch_bounds__(256) void softmax_kernel(
    const float* __restrict__ scores, u16* __restrict__ probs)
{
    const int row = blockIdx.x & (S - 1);
    const size_t base = (size_t)blockIdx.x * S;
    const int NW = (((row >> 6) * 64 + 64 + 127) >> 7) << 7;
    const float* sr = scores + base;
    u16* pr = probs + base;
    const int t4 = threadIdx.x * 4;
    const int lane = threadIdx.x & 63, wave = threadIdx.x >> 6;
    float4 v;
    if (t4 < NW) v = *(const float4*)(sr + t4);
    else v = make_float4(-3.4e38f, -3.4e38f, -3.4e38f, -3.4e38f);
    __shared__ float red[8];
    float m = fmaxf(fmaxf(v.x, v.y), fmaxf(v.z, v.w));
#pragma unroll
    for (int off = 32; off >= 1; off >>= 1) m = fmaxf(m, __shfl_xor(m, off));
    if (lane == 0) red[wave] = m;
    __syncthreads();
    m = fmaxf(fmaxf(red[0], red[1]), fmaxf(red[2], red[3]));
    float e0 = expf(v.x - m), e1 = expf(v.y - m), e2 = expf(v.z - m), e3 = expf(v.w - m);
    float s = e0 + e1 + e2 + e3;
#pragma unroll
    for (int off = 32; off >= 1; off >>= 1) s += __shfl_xor(s, off);
    __syncthreads();
    if (lane == 0) red[4 + wave] = s;
    __syncthreads();
    float invl = 1.0f / (red[4] + red[5] + red[6] + red[7]);
    if (t4 < NW) {
        u16 o[4] = { f2bf(e0 * invl), f2bf(e1 * invl), f2bf(e2 * invl), f2bf(e3 * invl) };
        *(unsigned long long*)(pr + t4) = *(unsigned long long*)o;
    }
}

// 4 tokens/block, one wave per token, coalesced float4 reads, shuffle reduce
__global__ __launch_bounds__(256) void router_kernel(
    const float* __restrict__ h2f, const float* __restrict__ rw,
    int* __restrict__ cnt, int* __restrict__ list, float* __restrict__ gates)
{
    const int t = blockIdx.x * 4 + (threadIdx.x >> 6);
    const int lane = threadIdx.x & 63;
    const float* hr = h2f + (size_t)t * DM;
    float acc[NE];
#pragma unroll
    for (int e = 0; e < NE; e++) acc[e] = 0.f;
#pragma unroll
    for (int i = 0; i < 8; i++) {
        int d0 = i * 256 + lane * 4;
        float4 h = *(const float4*)(hr + d0);
        float hv[4] = { h.x, h.y, h.z, h.w };
#pragma unroll
        for (int j = 0; j < 4; j++) {
            const float4 r0 = *(const float4*)(rw + (size_t)(d0 + j) * NE);
            const float4 r1 = *(const float4*)(rw + (size_t)(d0 + j) * NE + 4);
            acc[0] += hv[j] * r0.x; acc[1] += hv[j] * r0.y;
            acc[2] += hv[j] * r0.z; acc[3] += hv[j] * r0.w;
            acc[4] += hv[j] * r1.x; acc[5] += hv[j] * r1.y;
            acc[6] += hv[j] * r1.z; acc[7] += hv[j] * r1.w;
        }
    }
#pragma unroll
    for (int off = 32; off >= 1; off >>= 1)
#pragma unroll
        for (int e = 0; e < NE; e++) acc[e] += __shfl_xor(acc[e], off);
    if (lane == 0) {
        int e0 = 0; float m0 = acc[0];
#pragma unroll
        for (int q = 1; q < NE; q++) if (acc[q] > m0) { m0 = acc[q]; e0 = q; }
        int e1 = -1; float m1 = -3.4e38f;
#pragma unroll
        for (int q = 0; q < NE; q++) if (q != e0 && acc[q] > m1) { m1 = acc[q]; e1 = q; }
        float g0 = 1.0f / (1.0f + expf(m1 - m0));
        float g1 = 1.0f - g0;
        int p0 = atomicAdd(&cnt[e0], 1); list[e0 * S + p0] = t; gates[e0 * S + p0] = g0;
        int p1 = atomicAdd(&cnt[e1], 1); list[e1 * S + p1] = t; gates[e1 * S + p1] = g1;
    }
}

// ---------------------------------------------------------------------------
extern "C" void kernel_launch(void* const* d_in, const int* in_sizes, int n_in,
                              void* d_out, int out_size, void* d_ws, size_t ws_size,
                              hipStream_t stream)
{
    (void)in_sizes; (void)n_in; (void)out_size; (void)ws_size;
    const float* x     = (const float*)d_in[0];
    const int*   amask = (const int*)d_in[1];
    const int*   pos   = (const int*)d_in[2];
    const float* n1w   = (const float*)d_in[3];
    const float* n2w   = (const float*)d_in[4];
    const float* wqkv  = (const float*)d_in[5];
    const float* wout  = (const float*)d_in[6];
    const float* rw    = (const float*)d_in[7];
    const float* w1    = (const float*)d_in[8];
    const float* v1    = (const float*)d_in[9];
    const float* w2    = (const float*)d_in[10];
    float* out = (float*)d_out;

    char* p = (char*)d_ws;
    auto alloc = [&](size_t bytes) {
        char* r = p;
        p += (bytes + 255) & ~(size_t)255;
        return r;
    };
    float* resid  = (float*)alloc((size_t)S * DM * 4);
    float* h2f    = (float*)alloc((size_t)S * DM * 4);
    u16*   h2b    = (u16*)alloc((size_t)S * DM * 2);
    u16*   h1b    = (u16*)alloc((size_t)S * DM * 2);
    u16*   qb     = (u16*)alloc((size_t)S * NH * HD * 2);
    u16*   kb     = (u16*)alloc((size_t)S * NKV * HD * 2);
    u16*   vT     = (u16*)alloc((size_t)NKV * HD * S * 2);
    u16*   attnb  = (u16*)alloc((size_t)S * DM * 2);
    int*   cnt    = (int*)alloc(NE * 4);
    int*   list   = (int*)alloc((size_t)NE * S * 4);
    float* gates  = (float*)alloc((size_t)NE * S * 4);
    float* qkv    = (float*)alloc((size_t)S * QKVN * 4);
    u16*   wqkvT  = (u16*)alloc((size_t)QKVN * DM * 2);
    u16*   woutT  = (u16*)alloc((size_t)DM * DM * 2);
    u16*   wb     = (u16*)alloc((size_t)NE * FF * DM * 2);   // shared MoE weight buf (67MB)
    char*  arena  = alloc((size_t)NH * S * S * 4 + (size_t)NH * S * S * 2); // 96 MiB
    float* scores = (float*)arena;
    u16*   probs  = (u16*)(arena + (size_t)NH * S * S * 4);
    float* t1 = (float*)arena;                               // reuse after attention
    u16*   xx = (u16*)(arena + (size_t)NH * S * S * 4);

    // weight pre-pass: wqkv (K x N) -> bf16 N x K ; wout likewise
    transpose_kernel<<<dim3(QKVN / 32, DM / 32, 1), 256, 0, stream>>>(
        wqkv, QKVN, 0, wqkvT, DM, 0);
    transpose_kernel<<<dim3(DM / 32, DM / 32, 1), 256, 0, stream>>>(
        wout, DM, 0, woutT, DM, 0);

    // 1. LN1
    ln_kernel<<<S, 256, 0, stream>>>(x, n1w, h1b, nullptr, nullptr);
    // 2. QKV = clip(h1 @ wqkv)
    gemm_kernel<EPI_CLIP, false, false><<<dim3(QKVN / 128, S / 64, 1), 256, 0, stream>>>(
        h1b, DM, 0, wqkvT, DM, 0, 1, qkv, QKVN, 0, S, DM,
        nullptr, nullptr, nullptr, nullptr, nullptr, 0, nullptr, nullptr);
    // 3. RoPE q,k ; V^T (bf16, [NKV][HD][S])
    rope_kernel<<<(S * (NH + NKV) * 64) / 256, 256, 0, stream>>>(qkv, pos, qb, kb);
    transpose_kernel<<<dim3((NKV * HD) / 32, S / 32, 1), 256, 0, stream>>>(
        qkv + DM + NKV * HD, QKVN, 0, vT, S, 0);
    // 5. scores = Q@K^T/sqrt(HD), causal+mask (upper tiles skipped entirely)
    gemm_kernel<EPI_SCORES, false, false><<<dim3(S / 128, S / 64, NH), 256, 0, stream>>>(
        qb, NH * HD, HD, kb, NKV * HD, HD, NH / NKV, scores, S, (long)S * S, S, HD,
        nullptr, nullptr, nullptr, nullptr, nullptr, 0, nullptr, amask);
    // 6. softmax (causal span)
    softmax_kernel<<<NH * S, 256, 0, stream>>>(scores, probs);
    // 7. attn = P @ V (causal K-limit)
    gemm_kernel<EPI_BF16, true, false><<<dim3(HD / 128, S / 64, NH), 256, 0, stream>>>(
        probs, S, (long)S * S, vT, S, (long)HD * S, NH / NKV, attnb, DM, HD, S, S,
        nullptr, nullptr, nullptr, nullptr, nullptr, 0, nullptr, nullptr);
    // 8. resid = x + attn @ wout ; d_out = resid
    gemm_kernel<EPI_RESID, false, false><<<dim3(DM / 128, S / 64, 1), 256, 0, stream>>>(
        attnb, DM, 0, woutT, DM, 0, 1, resid, DM, 0, S, DM,
        nullptr, nullptr, nullptr, nullptr, x, 0, out, nullptr);
    // 9. LN2 (+ zero expert counters)
    ln_kernel<<<S, 256, 0, stream>>>(resid, n2w, h2b, h2f, cnt);
    // 10/11. router
    router_kernel<<<S / 4, 256, 0, stream>>>(h2f, rw, cnt, list, gates);
    // 12. t1 = gathered h2 @ w1[e]^T
    cvt_kernel<<<(int)(((long)NE * FF * DM / 8 + 255) / 256), 256, 0, stream>>>(
        w1, wb, (long)NE * FF * DM);
    gemm_kernel<EPI_F32, false, true><<<dim3(FF / 128, S / 64, NE), 256, 0, stream>>>(
        h2b, DM, 0, wb, DM, (long)FF * DM, 1, t1, FF, (long)S * FF, S, DM,
        list, nullptr, nullptr, cnt, nullptr, 0, nullptr, nullptr);
    // 13. xx = silu(t1) * (gathered h2 @ v1[e]^T)
    cvt_kernel<<<(int)(((long)NE * FF * DM / 8 + 255) / 256), 256, 0, stream>>>(
        v1, wb, (long)NE * FF * DM);
    gemm_kernel<EPI_SILUMUL, false, true><<<dim3(FF / 128, S / 64, NE), 256, 0, stream>>>(
        h2b, DM, 0, wb, DM, (long)FF * DM, 1, xx, FF, (long)S * FF, S, DM,
        list, nullptr, nullptr, cnt, t1, (long)S * FF, nullptr, nullptr);
    // 14. d_out[token] += gate * (xx @ w2[e])   (w2 F x D -> bf16 D x F)
    transpose_kernel<<<dim3(DM / 32, FF / 32, NE), 256, 0, stream>>>(
        w2, DM, (long)FF * DM, wb, FF, (long)DM * FF);
    gemm_kernel<EPI_SCATTER, false, false><<<dim3(DM / 128, S / 64, NE), 256, 0, stream>>>(
        xx, FF, (long)S * FF, wb, FF, (long)DM * FF, 1, out, DM, 0, S, FF,
        nullptr, list, gates, cnt, nullptr, 0, nullptr, nullptr);
}